// Round 1
// baseline (3497.137 us; speedup 1.0000x reference)
//
#include <hip/hip_runtime.h>
#include <hip/hip_bf16.h>
#include <cstdint>
#include <cstddef>

#define NU_ 100000
#define NI_ 50000
#define NN_ 150000
#define D_  64
#define NNZ_ 4000000
#define CN_ 200
#define CNNZ_ 5000
#define B_ 4096

// ---------------- CSR build ----------------

__global__ void k_hist(const int* __restrict__ rows, int* __restrict__ cnt) {
    int e = blockIdx.x * blockDim.x + threadIdx.x;
    if (e < NNZ_) atomicAdd(&cnt[rows[e]], 1);
}

__global__ void k_chunksum(const int* __restrict__ cnt, int* __restrict__ part) {
    __shared__ int s[1024];
    int i = blockIdx.x * 1024 + threadIdx.x;
    s[threadIdx.x] = (i < NN_) ? cnt[i] : 0;
    __syncthreads();
    for (int o = 512; o > 0; o >>= 1) {
        if (threadIdx.x < o) s[threadIdx.x] += s[threadIdx.x + o];
        __syncthreads();
    }
    if (threadIdx.x == 0) part[blockIdx.x] = s[0];
}

__global__ void k_scanpart(int* part, int nchunks, int* row_ptr) {
    if (threadIdx.x == 0 && blockIdx.x == 0) {
        int acc = 0;
        for (int i = 0; i < nchunks; i++) { int v = part[i]; part[i] = acc; acc += v; }
        row_ptr[NN_] = acc;
    }
}

__global__ void k_scanfinal(const int* __restrict__ cnt, const int* __restrict__ part,
                            int* __restrict__ row_ptr, int* __restrict__ cursor) {
    __shared__ int s[1024];
    int t = threadIdx.x;
    int i = blockIdx.x * 1024 + t;
    int v = (i < NN_) ? cnt[i] : 0;
    s[t] = v;
    __syncthreads();
    for (int o = 1; o < 1024; o <<= 1) {
        int x = (t >= o) ? s[t - o] : 0;
        __syncthreads();
        s[t] += x;
        __syncthreads();
    }
    if (i < NN_) {
        int ex = s[t] - v + part[blockIdx.x];
        row_ptr[i] = ex;
        cursor[i] = ex;
    }
}

__global__ void k_scatter(const int* __restrict__ rows, const int* __restrict__ cols,
                          const float* __restrict__ vals, int* __restrict__ cursor,
                          int* __restrict__ ccol, float* __restrict__ cval) {
    int e = blockIdx.x * blockDim.x + threadIdx.x;
    if (e < NNZ_) {
        int p = atomicAdd(&cursor[rows[e]], 1);
        ccol[p] = cols[e];
        cval[p] = vals[e];
    }
}

// ---------------- SpMM (one 64-lane wave per row, lane = dim) ----------------

template<bool EGO>
__global__ void k_spmm(const int* __restrict__ rp, const int* __restrict__ ci,
                       const float* __restrict__ cv, const float* __restrict__ x,
                       const float* __restrict__ ue, const float* __restrict__ ie,
                       float* __restrict__ xn, float* __restrict__ acc) {
    int w = (blockIdx.x * blockDim.x + threadIdx.x) >> 6;
    int lane = threadIdx.x & 63;
    if (w >= NN_) return;
    int j0 = rp[w], j1 = rp[w + 1];
    float s = 0.f;
    #pragma unroll 4
    for (int j = j0; j < j1; ++j) {
        int c = ci[j];
        float v = cv[j];
        float xv;
        if (EGO) xv = (c < NU_) ? ue[(size_t)c * D_ + lane]
                                : ie[(size_t)(c - NU_) * D_ + lane];
        else     xv = x[(size_t)c * D_ + lane];
        s += v * xv;
    }
    size_t o = (size_t)w * D_ + lane;
    xn[o] = s;
    if (EGO) {
        float eg = (w < NU_) ? ue[o] : ie[(size_t)(w - NU_) * D_ + lane];
        acc[o] = eg + s;   // acc = ego + x1
    } else {
        acc[o] += s;
    }
}

// ---------------- per-graph dot contribution ----------------

__global__ void k_dot_graph(const float* __restrict__ acc, const int* __restrict__ users,
                            const int* __restrict__ items, const int* __restrict__ negs,
                            float* __restrict__ out) {
    int w = (blockIdx.x * blockDim.x + threadIdx.x) >> 6;
    int lane = threadIdx.x & 63;
    if (w >= B_) return;
    int u = users[w], ip = items[w], in_ = negs[w];
    float du = acc[(size_t)u * D_ + lane];
    float di = acc[(size_t)(NU_ + ip) * D_ + lane] - acc[(size_t)(NU_ + in_) * D_ + lane];
    float p = du * di;
    for (int o = 32; o > 0; o >>= 1) p += __shfl_xor(p, o, 64);
    if (lane == 0) out[w] += p * 0.0625f;   // (1/4)^2
}

// ---------------- community projection: dst[c*64+d] += sum_u mat[u,c]*emb[u,d] ----------------

__global__ void k_proj(const float* __restrict__ mat, const float* __restrict__ emb,
                       int n, float* __restrict__ dst) {
    __shared__ float se[4][64];
    __shared__ float sc[4][100];
    int t = threadIdx.x;
    float a[25];
    #pragma unroll
    for (int k = 0; k < 25; k++) a[k] = 0.f;
    int upb = (n + gridDim.x - 1) / gridDim.x;
    int u0 = blockIdx.x * upb;
    int u1 = min(u0 + upb, n);
    for (int ub = u0; ub < u1; ub += 4) {
        int m = min(4, u1 - ub);
        if (t < m * 64) {
            int ul = t >> 6, d = t & 63;
            se[ul][d] = emb[(size_t)(ub + ul) * 64 + d];
        }
        for (int idx = t; idx < m * 100; idx += 256) {
            int ul = idx / 100, c = idx - ul * 100;
            sc[ul][c] = mat[(size_t)(ub + ul) * 100 + c];
        }
        __syncthreads();
        for (int ul = 0; ul < m; ++ul) {
            #pragma unroll
            for (int k = 0; k < 25; k++) {
                int pp = t + (k << 8);
                a[k] += sc[ul][pp >> 6] * se[ul][pp & 63];
            }
        }
        __syncthreads();
    }
    #pragma unroll
    for (int k = 0; k < 25; k++) {
        int pp = t + (k << 8);   // pp = c*64 + d
        atomicAdd(&dst[pp], a[k]);
    }
}

// ---------------- community GCN (tiny, edge-parallel atomics) ----------------

__global__ void k_cspmm(const int* __restrict__ r, const int* __restrict__ c,
                        const float* __restrict__ v, const float* __restrict__ x,
                        float* __restrict__ xn) {
    int w = (blockIdx.x * blockDim.x + threadIdx.x) >> 6;
    int lane = threadIdx.x & 63;
    if (w >= CNNZ_) return;
    int rr = r[w], cc = c[w];
    float vv = v[w];
    atomicAdd(&xn[rr * 64 + lane], vv * x[cc * 64 + lane]);
}

__global__ void k_cadd(const float* __restrict__ xn, float* __restrict__ acc) {
    int i = blockIdx.x * blockDim.x + threadIdx.x;
    if (i < CN_ * D_) acc[i] += xn[i];
}

// ---------------- community dot: out += (1/16)*<uc[u]@cacc_u, (ic[i]-ic[n])@cacc_i> ----------------

__global__ void k_dot_comm(const float* __restrict__ uc, const float* __restrict__ ic,
                           const float* __restrict__ cacc, const int* __restrict__ users,
                           const int* __restrict__ items, const int* __restrict__ negs,
                           float* __restrict__ out) {
    int w = (blockIdx.x * blockDim.x + threadIdx.x) >> 6;
    int lane = threadIdx.x & 63;
    if (w >= B_) return;
    int u = users[w], ip = items[w], in_ = negs[w];
    float u3 = 0.f, i3p = 0.f, i3n = 0.f;
    for (int cc = 0; cc < 100; ++cc) {
        float evU = cacc[cc * 64 + lane];
        float evI = cacc[(100 + cc) * 64 + lane];
        u3  += uc[(size_t)u * 100 + cc] * evU;
        i3p += ic[(size_t)ip * 100 + cc] * evI;
        i3n += ic[(size_t)in_ * 100 + cc] * evI;
    }
    float p = u3 * (i3p - i3n);
    for (int o = 32; o > 0; o >>= 1) p += __shfl_xor(p, o, 64);
    if (lane == 0) out[w] += p * 0.0625f;
}

// ---------------- launch ----------------

static inline char* alignp(char*& p, size_t bytes) {
    char* r = p;
    p += (bytes + 255) & ~(size_t)255;
    return r;
}

extern "C" void kernel_launch(void* const* d_in, const int* in_sizes, int n_in,
                              void* d_out, int out_size, void* d_ws, size_t ws_size,
                              hipStream_t stream) {
    const float* uemb = (const float*)d_in[0];
    const float* iemb = (const float*)d_in[1];
    const float* uc   = (const float*)d_in[11];
    const float* ic   = (const float*)d_in[12];
    const int*   cgr  = (const int*)d_in[13];
    const int*   cgc  = (const int*)d_in[14];
    const float* cgv  = (const float*)d_in[15];
    const int*   users = (const int*)d_in[16];
    const int*   items = (const int*)d_in[17];
    const int*   negs  = (const int*)d_in[18];
    float* out = (float*)d_out;

    char* p = (char*)d_ws;
    float* buf1   = (float*)alignp(p, (size_t)NN_ * D_ * 4);
    float* buf2   = (float*)alignp(p, (size_t)NN_ * D_ * 4);
    float* acc    = (float*)alignp(p, (size_t)NN_ * D_ * 4);
    int*   ccol   = (int*)  alignp(p, (size_t)NNZ_ * 4);
    float* cval   = (float*)alignp(p, (size_t)NNZ_ * 4);
    int*   row_ptr= (int*)  alignp(p, (size_t)(NN_ + 1) * 4);
    int*   cursor = (int*)  alignp(p, (size_t)NN_ * 4);
    int*   cnt    = (int*)  alignp(p, (size_t)NN_ * 4);
    int*   part   = (int*)  alignp(p, 1024 * 4);
    float* cego   = (float*)alignp(p, (size_t)CN_ * D_ * 4);
    float* cb1    = (float*)alignp(p, (size_t)CN_ * D_ * 4);
    float* cb2    = (float*)alignp(p, (size_t)CN_ * D_ * 4);
    float* cacc   = (float*)alignp(p, (size_t)CN_ * D_ * 4);

    const int NCH = (NN_ + 1023) / 1024;          // 147
    const int gE  = (NNZ_ + 255) / 256;           // edge-parallel grid
    const int gSp = (NN_ * 64) / 256;             // one wave per row
    const int gB  = (B_ * 64) / 256;              // one wave per batch elem
    const int gC  = (CNNZ_ * 64) / 256;
    const int gCA = (CN_ * D_) / 256;

    hipMemsetAsync(d_out, 0, (size_t)B_ * 4, stream);
    hipMemsetAsync(cego, 0, (size_t)CN_ * D_ * 4, stream);

    for (int g = 0; g < 3; ++g) {
        const int*   rows = (const int*)d_in[2 + g * 3];
        const int*   cols = (const int*)d_in[3 + g * 3];
        const float* vals = (const float*)d_in[4 + g * 3];

        hipMemsetAsync(cnt, 0, (size_t)NN_ * 4, stream);
        k_hist<<<gE, 256, 0, stream>>>(rows, cnt);
        k_chunksum<<<NCH, 1024, 0, stream>>>(cnt, part);
        k_scanpart<<<1, 64, 0, stream>>>(part, NCH, row_ptr);
        k_scanfinal<<<NCH, 1024, 0, stream>>>(cnt, part, row_ptr, cursor);
        k_scatter<<<gE, 256, 0, stream>>>(rows, cols, vals, cursor, ccol, cval);

        // layer 1: ego -> buf1, acc = ego + buf1
        k_spmm<true><<<gSp, 256, 0, stream>>>(row_ptr, ccol, cval, nullptr, uemb, iemb, buf1, acc);
        // layer 2: buf1 -> buf2, acc += buf2
        k_spmm<false><<<gSp, 256, 0, stream>>>(row_ptr, ccol, cval, buf1, nullptr, nullptr, buf2, acc);
        // layer 3: buf2 -> buf1, acc += buf1
        k_spmm<false><<<gSp, 256, 0, stream>>>(row_ptr, ccol, cval, buf2, nullptr, nullptr, buf1, acc);

        k_dot_graph<<<gB, 256, 0, stream>>>(acc, users, items, negs, out);
    }

    // community path
    k_proj<<<128, 256, 0, stream>>>(uc, uemb, NU_, cego);
    k_proj<<<128, 256, 0, stream>>>(ic, iemb, NI_, cego + 100 * 64);
    hipMemcpyAsync(cacc, cego, (size_t)CN_ * D_ * 4, hipMemcpyDeviceToDevice, stream);

    hipMemsetAsync(cb1, 0, (size_t)CN_ * D_ * 4, stream);
    k_cspmm<<<gC, 256, 0, stream>>>(cgr, cgc, cgv, cego, cb1);
    k_cadd<<<gCA, 256, 0, stream>>>(cb1, cacc);

    hipMemsetAsync(cb2, 0, (size_t)CN_ * D_ * 4, stream);
    k_cspmm<<<gC, 256, 0, stream>>>(cgr, cgc, cgv, cb1, cb2);
    k_cadd<<<gCA, 256, 0, stream>>>(cb2, cacc);

    hipMemsetAsync(cb1, 0, (size_t)CN_ * D_ * 4, stream);
    k_cspmm<<<gC, 256, 0, stream>>>(cgr, cgc, cgv, cb2, cb1);
    k_cadd<<<gCA, 256, 0, stream>>>(cb1, cacc);

    k_dot_comm<<<gB, 256, 0, stream>>>(uc, ic, cacc, users, items, negs, out);
}

// Round 2
// 2745.554 us; speedup vs baseline: 1.2737x; 1.2737x over previous
//
#include <hip/hip_runtime.h>
#include <hip/hip_bf16.h>
#include <cstdint>
#include <cstddef>

#define NU_ 100000
#define NI_ 50000
#define NN_ 150000
#define D_  64
#define NNZ_ 4000000
#define CN_ 200
#define CNNZ_ 5000
#define B_ 4096

// ---------------- CSR build ----------------

__global__ void k_hist(const int* __restrict__ rows, int* __restrict__ cnt) {
    int e = blockIdx.x * blockDim.x + threadIdx.x;
    if (e < NNZ_) atomicAdd(&cnt[rows[e]], 1);
}

__global__ void k_chunksum(const int* __restrict__ cnt, int* __restrict__ part) {
    __shared__ int s[1024];
    int i = blockIdx.x * 1024 + threadIdx.x;
    s[threadIdx.x] = (i < NN_) ? cnt[i] : 0;
    __syncthreads();
    for (int o = 512; o > 0; o >>= 1) {
        if (threadIdx.x < o) s[threadIdx.x] += s[threadIdx.x + o];
        __syncthreads();
    }
    if (threadIdx.x == 0) part[blockIdx.x] = s[0];
}

__global__ void k_scanpart(int* part, int nchunks, int* row_ptr) {
    if (threadIdx.x == 0 && blockIdx.x == 0) {
        int acc = 0;
        for (int i = 0; i < nchunks; i++) { int v = part[i]; part[i] = acc; acc += v; }
        row_ptr[NN_] = acc;
    }
}

__global__ void k_scanfinal(const int* __restrict__ cnt, const int* __restrict__ part,
                            int* __restrict__ row_ptr, int* __restrict__ cursor) {
    __shared__ int s[1024];
    int t = threadIdx.x;
    int i = blockIdx.x * 1024 + t;
    int v = (i < NN_) ? cnt[i] : 0;
    s[t] = v;
    __syncthreads();
    for (int o = 1; o < 1024; o <<= 1) {
        int x = (t >= o) ? s[t - o] : 0;
        __syncthreads();
        s[t] += x;
        __syncthreads();
    }
    if (i < NN_) {
        int ex = s[t] - v + part[blockIdx.x];
        row_ptr[i] = ex;
        cursor[i] = ex;
    }
}

__global__ void k_scatter(const int* __restrict__ rows, const int* __restrict__ cols,
                          const float* __restrict__ vals, int* __restrict__ cursor,
                          int2* __restrict__ ep) {
    int e = blockIdx.x * blockDim.x + threadIdx.x;
    if (e < NNZ_) {
        int p = atomicAdd(&cursor[rows[e]], 1);
        ep[p] = make_int2(cols[e], __float_as_int(vals[e]));
    }
}

// ---------------- SpMM: one wave per row, 4 edges in flight, float4 lanes ----------------

template<bool EGO>
__global__ __launch_bounds__(256) void k_spmm(const int* __restrict__ rp,
                                              const int2* __restrict__ ep,
                                              const float* __restrict__ x,
                                              const float* __restrict__ ue,
                                              const float* __restrict__ ie,
                                              float* __restrict__ xn) {
    int w = (blockIdx.x * 256 + threadIdx.x) >> 6;
    if (w >= NN_) return;
    int lane = threadIdx.x & 63;
    int quarter = lane >> 4;      // which of 4 concurrent edges
    int l16 = lane & 15;          // 16 lanes x float4 = 64 dims
    int j0 = rp[w], j1 = rp[w + 1];
    float4 s = make_float4(0.f, 0.f, 0.f, 0.f);
    #pragma unroll 2
    for (int j = j0; j < j1; j += 4) {
        int je = j + quarter;
        int2 e = (je < j1) ? ep[je] : make_int2(0, 0);
        int c = e.x;
        float v = __int_as_float(e.y);
        const float* src;
        if (EGO) src = (c < NU_) ? ue + (size_t)c * D_ : ie + (size_t)(c - NU_) * D_;
        else     src = x + (size_t)c * D_;
        float4 xv = *(const float4*)(src + l16 * 4);
        s.x += v * xv.x; s.y += v * xv.y; s.z += v * xv.z; s.w += v * xv.w;
    }
    // combine the 4 quarter-partials
    s.x += __shfl_xor(s.x, 32, 64); s.y += __shfl_xor(s.y, 32, 64);
    s.z += __shfl_xor(s.z, 32, 64); s.w += __shfl_xor(s.w, 32, 64);
    s.x += __shfl_xor(s.x, 16, 64); s.y += __shfl_xor(s.y, 16, 64);
    s.z += __shfl_xor(s.z, 16, 64); s.w += __shfl_xor(s.w, 16, 64);
    if (lane < 16) *(float4*)(xn + (size_t)w * D_ + l16 * 4) = s;
}

// ---------------- per-graph dot contribution (reads ego + 3 layer buffers) ----------------

__global__ void k_dot_graph(const float* __restrict__ ue, const float* __restrict__ ie,
                            const float* __restrict__ x1, const float* __restrict__ x2,
                            const float* __restrict__ x3,
                            const int* __restrict__ users, const int* __restrict__ items,
                            const int* __restrict__ negs, float* __restrict__ out) {
    int w = (blockIdx.x * blockDim.x + threadIdx.x) >> 6;
    int lane = threadIdx.x & 63;
    if (w >= B_) return;
    int u = users[w], ip = items[w], in_ = negs[w];
    size_t ou = (size_t)u * D_ + lane;
    size_t oi = (size_t)(NU_ + ip) * D_ + lane;
    size_t on = (size_t)(NU_ + in_) * D_ + lane;
    float du = ue[(size_t)u * D_ + lane]   + x1[ou] + x2[ou] + x3[ou];
    float di = ie[(size_t)ip * D_ + lane]  + x1[oi] + x2[oi] + x3[oi];
    float dn = ie[(size_t)in_ * D_ + lane] + x1[on] + x2[on] + x3[on];
    float p = du * (di - dn);
    for (int o = 32; o > 0; o >>= 1) p += __shfl_xor(p, o, 64);
    if (lane == 0) out[w] += p * 0.0625f;   // (1/4)^2
}

// ---------------- community projection: dst[c*64+d] += sum_u mat[u,c]*emb[u,d] ----------------

__global__ __launch_bounds__(256) void k_proj(const float* __restrict__ mat,
                                              const float* __restrict__ emb,
                                              int n, float* __restrict__ dst) {
    __shared__ float se[8 * 64];
    __shared__ float sc[8 * 100];
    int t = threadIdx.x;
    int d = t & 63, c0 = t >> 6;
    float a[25];
    #pragma unroll
    for (int k = 0; k < 25; k++) a[k] = 0.f;

    int upb = (n + gridDim.x - 1) / gridDim.x;
    int u0 = blockIdx.x * upb;
    int u1 = min(u0 + upb, n);
    int ub = u0;
    // fast path: full batches of 8 users, float4 cooperative loads
    for (; ub + 8 <= u1; ub += 8) {
        const float4* e4 = (const float4*)(emb + (size_t)ub * 64);
        const float4* c4 = (const float4*)(mat + (size_t)ub * 100);
        float4* se4 = (float4*)se;
        float4* sc4 = (float4*)sc;
        for (int idx = t; idx < 328; idx += 256) {
            if (idx < 128) se4[idx] = e4[idx];
            else           sc4[idx - 128] = c4[idx - 128];
        }
        __syncthreads();
        #pragma unroll
        for (int ul = 0; ul < 8; ++ul) {
            float ev = se[(ul << 6) + d];
            #pragma unroll
            for (int k = 0; k < 25; k++)
                a[k] += sc[ul * 100 + c0 + (k << 2)] * ev;
        }
        __syncthreads();
    }
    // tail
    if (ub < u1) {
        int m = u1 - ub;
        for (int idx = t; idx < m * 64; idx += 256) se[idx] = emb[(size_t)ub * 64 + idx];
        for (int idx = t; idx < m * 100; idx += 256) sc[idx] = mat[(size_t)ub * 100 + idx];
        __syncthreads();
        for (int ul = 0; ul < m; ++ul) {
            float ev = se[(ul << 6) + d];
            #pragma unroll
            for (int k = 0; k < 25; k++)
                a[k] += sc[ul * 100 + c0 + (k << 2)] * ev;
        }
    }
    #pragma unroll
    for (int k = 0; k < 25; k++)
        atomicAdd(&dst[t + (k << 8)], a[k]);   // t + k*256 == c*64 + d
}

// ---------------- community GCN (tiny, edge-parallel atomics) ----------------

__global__ void k_cspmm(const int* __restrict__ r, const int* __restrict__ c,
                        const float* __restrict__ v, const float* __restrict__ x,
                        float* __restrict__ xn) {
    int w = (blockIdx.x * blockDim.x + threadIdx.x) >> 6;
    int lane = threadIdx.x & 63;
    if (w >= CNNZ_) return;
    int rr = r[w], cc = c[w];
    float vv = v[w];
    atomicAdd(&xn[rr * 64 + lane], vv * x[cc * 64 + lane]);
}

__global__ void k_cadd(const float* __restrict__ xn, float* __restrict__ acc) {
    int i = blockIdx.x * blockDim.x + threadIdx.x;
    if (i < CN_ * D_) acc[i] += xn[i];
}

// ---------------- community dot ----------------

__global__ void k_dot_comm(const float* __restrict__ uc, const float* __restrict__ ic,
                           const float* __restrict__ cacc, const int* __restrict__ users,
                           const int* __restrict__ items, const int* __restrict__ negs,
                           float* __restrict__ out) {
    int w = (blockIdx.x * blockDim.x + threadIdx.x) >> 6;
    int lane = threadIdx.x & 63;
    if (w >= B_) return;
    int u = users[w], ip = items[w], in_ = negs[w];
    float u3 = 0.f, i3p = 0.f, i3n = 0.f;
    for (int cc = 0; cc < 100; ++cc) {
        float evU = cacc[cc * 64 + lane];
        float evI = cacc[(100 + cc) * 64 + lane];
        u3  += uc[(size_t)u * 100 + cc] * evU;
        i3p += ic[(size_t)ip * 100 + cc] * evI;
        i3n += ic[(size_t)in_ * 100 + cc] * evI;
    }
    float p = u3 * (i3p - i3n);
    for (int o = 32; o > 0; o >>= 1) p += __shfl_xor(p, o, 64);
    if (lane == 0) out[w] += p * 0.0625f;
}

// ---------------- launch ----------------

static inline char* alignp(char*& p, size_t bytes) {
    char* r = p;
    p += (bytes + 255) & ~(size_t)255;
    return r;
}

extern "C" void kernel_launch(void* const* d_in, const int* in_sizes, int n_in,
                              void* d_out, int out_size, void* d_ws, size_t ws_size,
                              hipStream_t stream) {
    const float* uemb = (const float*)d_in[0];
    const float* iemb = (const float*)d_in[1];
    const float* uc   = (const float*)d_in[11];
    const float* ic   = (const float*)d_in[12];
    const int*   cgr  = (const int*)d_in[13];
    const int*   cgc  = (const int*)d_in[14];
    const float* cgv  = (const float*)d_in[15];
    const int*   users = (const int*)d_in[16];
    const int*   items = (const int*)d_in[17];
    const int*   negs  = (const int*)d_in[18];
    float* out = (float*)d_out;

    char* p = (char*)d_ws;
    float* x1     = (float*)alignp(p, (size_t)NN_ * D_ * 4);
    float* x2     = (float*)alignp(p, (size_t)NN_ * D_ * 4);
    float* x3     = (float*)alignp(p, (size_t)NN_ * D_ * 4);
    int2*  ep     = (int2*) alignp(p, (size_t)NNZ_ * 8);
    int*   row_ptr= (int*)  alignp(p, (size_t)(NN_ + 1) * 4);
    int*   cursor = (int*)  alignp(p, (size_t)NN_ * 4);
    int*   cnt    = (int*)  alignp(p, (size_t)NN_ * 4);
    int*   part   = (int*)  alignp(p, 1024 * 4);
    float* cego   = (float*)alignp(p, (size_t)CN_ * D_ * 4);
    float* cb1    = (float*)alignp(p, (size_t)CN_ * D_ * 4);
    float* cb2    = (float*)alignp(p, (size_t)CN_ * D_ * 4);
    float* cacc   = (float*)alignp(p, (size_t)CN_ * D_ * 4);

    const int NCH = (NN_ + 1023) / 1024;
    const int gE  = (NNZ_ + 255) / 256;
    const int gSp = (NN_ * 64) / 256;
    const int gB  = (B_ * 64) / 256;
    const int gC  = (CNNZ_ * 64) / 256;
    const int gCA = (CN_ * D_) / 256;

    hipMemsetAsync(d_out, 0, (size_t)B_ * 4, stream);
    hipMemsetAsync(cego, 0, (size_t)CN_ * D_ * 4, stream);

    for (int g = 0; g < 3; ++g) {
        const int*   rows = (const int*)d_in[2 + g * 3];
        const int*   cols = (const int*)d_in[3 + g * 3];
        const float* vals = (const float*)d_in[4 + g * 3];

        hipMemsetAsync(cnt, 0, (size_t)NN_ * 4, stream);
        k_hist<<<gE, 256, 0, stream>>>(rows, cnt);
        k_chunksum<<<NCH, 1024, 0, stream>>>(cnt, part);
        k_scanpart<<<1, 64, 0, stream>>>(part, NCH, row_ptr);
        k_scanfinal<<<NCH, 1024, 0, stream>>>(cnt, part, row_ptr, cursor);
        k_scatter<<<gE, 256, 0, stream>>>(rows, cols, vals, cursor, ep);

        k_spmm<true ><<<gSp, 256, 0, stream>>>(row_ptr, ep, nullptr, uemb, iemb, x1);
        k_spmm<false><<<gSp, 256, 0, stream>>>(row_ptr, ep, x1, nullptr, nullptr, x2);
        k_spmm<false><<<gSp, 256, 0, stream>>>(row_ptr, ep, x2, nullptr, nullptr, x3);

        k_dot_graph<<<gB, 256, 0, stream>>>(uemb, iemb, x1, x2, x3, users, items, negs, out);
    }

    // community path
    k_proj<<<512, 256, 0, stream>>>(uc, uemb, NU_, cego);
    k_proj<<<512, 256, 0, stream>>>(ic, iemb, NI_, cego + 100 * 64);
    hipMemcpyAsync(cacc, cego, (size_t)CN_ * D_ * 4, hipMemcpyDeviceToDevice, stream);

    hipMemsetAsync(cb1, 0, (size_t)CN_ * D_ * 4, stream);
    k_cspmm<<<gC, 256, 0, stream>>>(cgr, cgc, cgv, cego, cb1);
    k_cadd<<<gCA, 256, 0, stream>>>(cb1, cacc);

    hipMemsetAsync(cb2, 0, (size_t)CN_ * D_ * 4, stream);
    k_cspmm<<<gC, 256, 0, stream>>>(cgr, cgc, cgv, cb1, cb2);
    k_cadd<<<gCA, 256, 0, stream>>>(cb2, cacc);

    hipMemsetAsync(cb1, 0, (size_t)CN_ * D_ * 4, stream);
    k_cspmm<<<gC, 256, 0, stream>>>(cgr, cgc, cgv, cb2, cb1);
    k_cadd<<<gCA, 256, 0, stream>>>(cb1, cacc);

    k_dot_comm<<<gB, 256, 0, stream>>>(uc, ic, cacc, users, items, negs, out);
}